// Round 1
// baseline (6474.078 us; speedup 1.0000x reference)
//
#include <hip/hip_runtime.h>
#include <hip/hip_fp16.h>

#define TCH 256
#define NCH 4

typedef __attribute__((ext_vector_type(8))) _Float16 half8;
typedef __attribute__((ext_vector_type(2))) _Float16 half2v;
typedef __attribute__((ext_vector_type(4))) float floatx4;

__device__ __forceinline__ float dot2f(unsigned a, unsigned b, float c) {
#if __has_builtin(__builtin_amdgcn_fdot2)
  return __builtin_amdgcn_fdot2(__builtin_bit_cast(half2v, a),
                                __builtin_bit_cast(half2v, b), c, false);
#else
  __half2 x = __builtin_bit_cast(__half2, a);
  __half2 y = __builtin_bit_cast(__half2, b);
  c = fmaf(__half2float(x.x), __half2float(y.x), c);
  c = fmaf(__half2float(x.y), __half2float(y.y), c);
  return c;
#endif
}

// ---------------- GEMM: C[m,n] = A[m,:] . B[n,:]  (B row-major [N][K], fp32)
// A is f16 (or fp32 for MLP1), staged to LDS as f16; MFMA 16x16x32 f16.
// M = 32768 (chunk rows, m = b*TCH + t), tiles 128x128, BK=32.
template<bool AF32, bool RELUB>
__global__ __launch_bounds__(256, 2) void gemm_k(
    const void* __restrict__ Ab, const float* __restrict__ Bw,
    const float* __restrict__ bias, __half* __restrict__ C,
    const int* __restrict__ length, int K, int KT, int N, int arst, int t0)
{
  int b = blockIdx.x >> 1;                  // 2 m-tiles (128 rows) per batch elem
  int tloc0 = (blockIdx.x & 1) << 7;
  if (t0 + tloc0 >= length[b]) return;      // whole tile beyond ragged length

  __shared__ half8 As[128][5];              // [row][k-group of 8], 40 f16/row (pad)
  __shared__ half8 Bs[128][5];

  int tid = threadIdx.x;
  int wave = tid >> 6, lane = tid & 63;
  int wm = (wave & 1) << 6, wn = (wave >> 1) << 6;
  int quad = lane >> 4, sub = lane & 15;
  int n0 = blockIdx.y << 7;

  floatx4 acc[4][4];
#pragma unroll
  for (int i = 0; i < 4; ++i)
#pragma unroll
    for (int j = 0; j < 4; ++j)
#pragma unroll
      for (int e = 0; e < 4; ++e) acc[i][j][e] = 0.f;

  size_t arowbase = (size_t)b * arst + tloc0;

  for (int kt = 0; kt < KT; ++kt) {
    int k0 = kt << 5;
#pragma unroll
    for (int pass = 0; pass < 2; ++pass) {
      int idx = tid + (pass << 8);
      int r = idx >> 2, c8 = (idx & 3) << 3;
      int kb = k0 + c8;
      // ---- A tile
      half8 v;
      if (AF32) {
        const float* src = (const float*)Ab + (arowbase + r) * K + kb;
        if (kb + 8 <= K) {
          float4 u0 = *(const float4*)(src);
          float4 u1 = *(const float4*)(src + 4);
          v[0] = (_Float16)u0.x; v[1] = (_Float16)u0.y; v[2] = (_Float16)u0.z; v[3] = (_Float16)u0.w;
          v[4] = (_Float16)u1.x; v[5] = (_Float16)u1.y; v[6] = (_Float16)u1.z; v[7] = (_Float16)u1.w;
        } else {
#pragma unroll
          for (int i = 0; i < 8; ++i) v[i] = (kb + i < K) ? (_Float16)src[i] : (_Float16)0.f;
        }
      } else {
        const __half* src = (const __half*)Ab + (arowbase + r) * K + kb;
        if (kb + 8 <= K) v = *(const half8*)src;
        else {
#pragma unroll
          for (int i = 0; i < 8; ++i) v[i] = (kb + i < K) ? *(const _Float16*)(src + i) : (_Float16)0.f;
        }
      }
      As[r][c8 >> 3] = v;
      // ---- B tile (always fp32 weights [N][K])
      const float* bsrc = Bw + (size_t)(n0 + r) * K + kb;
      half8 w;
      if (kb + 8 <= K) {
        float4 u0 = *(const float4*)(bsrc);
        float4 u1 = *(const float4*)(bsrc + 4);
        w[0] = (_Float16)u0.x; w[1] = (_Float16)u0.y; w[2] = (_Float16)u0.z; w[3] = (_Float16)u0.w;
        w[4] = (_Float16)u1.x; w[5] = (_Float16)u1.y; w[6] = (_Float16)u1.z; w[7] = (_Float16)u1.w;
      } else {
#pragma unroll
        for (int i = 0; i < 8; ++i) w[i] = (kb + i < K) ? (_Float16)bsrc[i] : (_Float16)0.f;
      }
      Bs[r][c8 >> 3] = w;
    }
    __syncthreads();
    half8 af[4], bf[4];
#pragma unroll
    for (int i = 0; i < 4; ++i) {
      af[i] = As[wm + (i << 4) + sub][quad];
      bf[i] = Bs[wn + (i << 4) + sub][quad];
    }
#pragma unroll
    for (int mt = 0; mt < 4; ++mt)
#pragma unroll
      for (int nt = 0; nt < 4; ++nt)
        acc[mt][nt] = __builtin_amdgcn_mfma_f32_16x16x32_f16(af[mt], bf[nt], acc[mt][nt], 0, 0, 0);
    __syncthreads();
  }
  // epilogue: D layout col=lane&15 (n), row=quad*4+reg (m)  [m89-verified]
  size_t mrowbase = (size_t)blockIdx.x << 7;
#pragma unroll
  for (int nt = 0; nt < 4; ++nt) {
    int n = n0 + wn + (nt << 4) + sub;
    float bv = 0.f;
    if (RELUB) bv = bias[n];
#pragma unroll
    for (int mt = 0; mt < 4; ++mt) {
#pragma unroll
      for (int r4 = 0; r4 < 4; ++r4) {
        int m = wm + (mt << 4) + (quad << 2) + r4;
        float v = acc[mt][nt][r4] + bv;
        if (RELUB) v = fmaxf(v, 0.f);
        C[(mrowbase + m) * (size_t)N + n] = __float2half(v);
      }
    }
  }
}

// ---------------- LSTM scan: 2 WGs per batch elem (hf = which 128-half of H).
// Thread owns gate-row = gate*256 + hf*128 + hl; W_hh row f16-pair-packed in 128 VGPRs.
// h broadcast: pairs distributed 1/lane, v_readlane + v_dot2_f32_f16.
// Cross-WG h-half exchange: 64-bit agent-scope atomics, tag(step)<<32 | pair,
// parity double-buffered. 0xAA poison reads as negative tag -> spin-safe, no init.
__global__ __launch_bounds__(512, 2) void scan_k(
    const __half* __restrict__ xg, const float* __restrict__ whh,
    const float* __restrict__ bih, const float* __restrict__ bhh,
    __half* __restrict__ hout, unsigned* __restrict__ hstate,
    float* __restrict__ cstate, unsigned long long* __restrict__ exch,
    const int* __restrict__ length, int t0)
{
  int b = blockIdx.x >> 1, hf = blockIdx.x & 1;
  int len = length[b];
  int tend = min(t0 + TCH, len);
  if (t0 >= tend) return;

  int tid = threadIdx.x;
  int lane = tid & 63;
  int gate = tid >> 7, hl = tid & 127;
  int row = (gate << 8) + (hf << 7) + hl;

  __shared__ float gbuf[512];
  __shared__ unsigned short hbf[128];
  __shared__ unsigned opair[64];

  // ---- load W_hh row, pack f16 pairs, permuted: [0,64)=own half pairs, [64,128)=partner
  unsigned wp[128];
  {
    const float* wsrc = whh + (size_t)row * 256;
#pragma unroll
    for (int p2 = 0; p2 < 64; ++p2) {
      float4 f = *(const float4*)(wsrc + (p2 << 2));
      unsigned pk0 = ((unsigned)__half_as_ushort(__float2half(f.y)) << 16) | __half_as_ushort(__float2half(f.x));
      unsigned pk1 = ((unsigned)__half_as_ushort(__float2half(f.w)) << 16) | __half_as_ushort(__float2half(f.z));
      int p = p2 << 1;
      int pj0 = ((p >> 6) == hf) ? (p & 63) : (64 + (p & 63));
      int pa = p + 1;
      int pj1 = ((pa >> 6) == hf) ? (pa & 63) : (64 + (pa & 63));
      wp[pj0] = pk0;
      wp[pj1] = pk1;
    }
  }
  float biasr = bih[row] + bhh[row];

  unsigned hp0 = 0, hp1 = 0;   // own-half pairs (lane l = pair hf*64+l), partner pairs
  float cv = 0.f;
  if (t0 > 0) {
    hp0 = hstate[(b << 7) + (hf << 6) + lane];
    hp1 = hstate[(b << 7) + ((1 - hf) << 6) + lane];
    if (tid < 128) cv = cstate[(b << 8) + (hf << 7) + tid];
  }

  const __half* xgp = xg + ((size_t)b * TCH) * 1024 + row;
  unsigned long long* exA = exch + ((((size_t)b << 1) | (size_t)hf) << 7);
  unsigned long long* exB = exch + ((((size_t)b << 1) | (size_t)(1 - hf)) << 7);

  for (int t = t0; t < tend; ++t) {
    float xgv = __half2float(xgp[(size_t)(t - t0) << 10]);  // issued early, used late
    float acc = biasr;
    // phase 1: own-half pairs (available immediately -> hides partner latency)
#pragma unroll
    for (int j = 0; j < 64; ++j)
      acc = dot2f(wp[j], (unsigned)__builtin_amdgcn_readlane(hp0, j), acc);
    // partner half of h^t
    if (t > t0) {
      const unsigned long long* pw = exB + ((t & 1) << 6) + lane;
      unsigned long long w = __hip_atomic_load(pw, __ATOMIC_RELAXED, __HIP_MEMORY_SCOPE_AGENT);
      while ((int)(unsigned)(w >> 32) != t) {
        __builtin_amdgcn_s_sleep(2);
        w = __hip_atomic_load(pw, __ATOMIC_RELAXED, __HIP_MEMORY_SCOPE_AGENT);
      }
      hp1 = (unsigned)w;
    }
#pragma unroll
    for (int j = 0; j < 64; ++j)
      acc = dot2f(wp[64 + j], (unsigned)__builtin_amdgcn_readlane(hp1, j), acc);
    acc += xgv;
    // nonlinearity (wave-uniform branch: gate = tid>>7)
    float gv = (gate == 2) ? tanhf(acc) : (1.f / (1.f + __expf(-acc)));
    gbuf[tid] = gv;
    __syncthreads();
    if (tid < 128) {
      float iv = gbuf[tid], fv = gbuf[128 + tid], gg = gbuf[256 + tid], ov = gbuf[384 + tid];
      cv = fv * cv + iv * gg;
      float hv = ov * tanhf(cv);
      __half hh = __float2half(hv);
      hout[(((size_t)b * TCH) + (t - t0)) * 256 + (hf << 7) + tid] = hh;
      hbf[tid] = __half_as_ushort(hh);
    }
    __syncthreads();
    if (tid < 64) {
      unsigned pr = ((unsigned)hbf[(tid << 1) + 1] << 16) | hbf[tid << 1];
      opair[tid] = pr;
      __hip_atomic_store(exA + (((t + 1) & 1) << 6) + tid,
                         ((unsigned long long)(unsigned)(t + 1) << 32) | (unsigned long long)pr,
                         __ATOMIC_RELAXED, __HIP_MEMORY_SCOPE_AGENT);
    }
    __syncthreads();
    hp0 = opair[lane];
  }
  if (tid < 64) hstate[(b << 7) + (hf << 6) + tid] = hp0;
  if (tid < 128) cstate[(b << 8) + (hf << 7) + tid] = cv;
}

// ---------------- head: decision = h2 . Wd + bd, ragged-masked sum, final /len
__global__ __launch_bounds__(256, 2) void head_k(
    const __half* __restrict__ h2, const float* __restrict__ Wd,
    const float* __restrict__ bd, const int* __restrict__ length,
    float* __restrict__ dacc, float* __restrict__ out, int t0, int first, int last)
{
  int b = blockIdx.x, tid = threadIdx.x;
  int lane = tid & 63, wave = tid >> 6;
  int len = length[b];
  int tend = min(t0 + TCH, len);
  float4 w4 = *(const float4*)(Wd + (lane << 2));
  float wsum = 0.f;
  for (int t = t0 + wave; t < tend; t += 4) {
    const __half* hr = h2 + (((size_t)b * TCH) + (t - t0)) * 256 + (lane << 2);
    uint2 u = *(const uint2*)hr;
    __half2 p0 = __builtin_bit_cast(__half2, u.x);
    __half2 p1 = __builtin_bit_cast(__half2, u.y);
    float s = w4.x * __half2float(p0.x) + w4.y * __half2float(p0.y)
            + w4.z * __half2float(p1.x) + w4.w * __half2float(p1.y);
#pragma unroll
    for (int off = 32; off > 0; off >>= 1) s += __shfl_xor(s, off);
    wsum += s;    // s is full-wave sum, counted once via lane0 below
  }
  __shared__ float wred[4];
  if (lane == 0) wred[wave] = wsum;
  __syncthreads();
  if (tid == 0) {
    int cnt = tend - t0; if (cnt < 0) cnt = 0;
    float tot = wred[0] + wred[1] + wred[2] + wred[3] + bd[0] * (float)cnt;
    if (!first) tot += dacc[b];
    dacc[b] = tot;
    if (last) out[b] = tot / (float)len;
  }
}

extern "C" void kernel_launch(void* const* d_in, const int* in_sizes, int n_in,
                              void* d_out, int out_size, void* d_ws, size_t ws_size,
                              hipStream_t stream) {
  (void)in_sizes; (void)n_in; (void)out_size; (void)ws_size;
  const float* x    = (const float*)d_in[0];
  const int* length = (const int*)d_in[1];
  const float* W1   = (const float*)d_in[2];
  const float* b1   = (const float*)d_in[3];
  const float* W2   = (const float*)d_in[4];
  const float* b2   = (const float*)d_in[5];
  const float* wih[3] = {(const float*)d_in[6],  (const float*)d_in[10], (const float*)d_in[14]};
  const float* whh[3] = {(const float*)d_in[7],  (const float*)d_in[11], (const float*)d_in[15]};
  const float* bih[3] = {(const float*)d_in[8],  (const float*)d_in[12], (const float*)d_in[16]};
  const float* bhh[3] = {(const float*)d_in[9],  (const float*)d_in[13], (const float*)d_in[17]};
  const float* Wd   = (const float*)d_in[18];
  const float* bd   = (const float*)d_in[19];
  float* out = (float*)d_out;

  char* ws = (char*)d_ws;
  __half* XG    = (__half*)(ws);                     // 32768 x 1024 f16 = 64 MiB
  __half* FEAT1 = (__half*)(ws + 67108864);          // 32768 x 256  f16 = 16 MiB
  __half* FEAT2 = (__half*)(ws + 83886080);          // 32768 x 512  f16 = 32 MiB
  __half* HBUF  = (__half*)(ws + 117440512);         // 32768 x 256  f16 = 16 MiB
  unsigned* HST = (unsigned*)(ws + 134217728);               // 3 x 16384 u32
  float* CST    = (float*)(ws + 134217728 + 196608);         // 3 x 32768 f32
  unsigned long long* EXC = (unsigned long long*)(ws + 134217728 + 589824);  // 3 x 32768 u64
  float* DACC   = (float*)(ws + 134217728 + 589824 + 786432);

  for (int c = 0; c < NCH; ++c) {
    int t0 = c * TCH;
    // MLP1: x[.,136] -> 256, relu
    gemm_k<true,  true ><<<dim3(256, 2), 256, 0, stream>>>(
        (const void*)(x + (size_t)t0 * 136), W1, b1, FEAT1, length, 136, 5, 256, 1024, t0);
    // MLP2: 256 -> 512, relu
    gemm_k<false, true ><<<dim3(256, 4), 256, 0, stream>>>(
        (const void*)FEAT1, W2, b2, FEAT2, length, 256, 8, 512, TCH, t0);
    // layer 0
    gemm_k<false, false><<<dim3(256, 8), 256, 0, stream>>>(
        (const void*)FEAT2, wih[0], nullptr, XG, length, 512, 16, 1024, TCH, t0);
    scan_k<<<256, 512, 0, stream>>>(XG, whh[0], bih[0], bhh[0], HBUF,
                                    HST, CST, EXC, length, t0);
    // layer 1
    gemm_k<false, false><<<dim3(256, 8), 256, 0, stream>>>(
        (const void*)HBUF, wih[1], nullptr, XG, length, 256, 8, 1024, TCH, t0);
    scan_k<<<256, 512, 0, stream>>>(XG, whh[1], bih[1], bhh[1], HBUF,
                                    HST + 16384, CST + 32768, EXC + 32768, length, t0);
    // layer 2
    gemm_k<false, false><<<dim3(256, 8), 256, 0, stream>>>(
        (const void*)HBUF, wih[2], nullptr, XG, length, 256, 8, 1024, TCH, t0);
    scan_k<<<256, 512, 0, stream>>>(XG, whh[2], bih[2], bhh[2], HBUF,
                                    HST + 32768, CST + 65536, EXC + 65536, length, t0);
    // head + ragged mean
    head_k<<<128, 256, 0, stream>>>(HBUF, Wd, bd, length, DACC, out, t0, c == 0, c == NCH - 1);
  }
}